// Round 5
// baseline (579.480 us; speedup 1.0000x reference)
//
#include <hip/hip_runtime.h>
#include <math.h>

// GrapsuleNet forward:
//  K1 k_mean   : xm[b,c] = mean_n x[b,c,n]                        (reads x, 201MB)
//  K2 k_qk     : q = xm@qwT+qb; qk_t[b,c,h] = (1/4)*sum_d q*kw    (kb dropped: softmax-invariant)
//  K3 k_logits : logits[b,h,n] = sum_c x[b,c,n]*qk_t[b,c,h]       (reads x, 201MB; qk via s_load)
//                + per-block softmax partials (m, s, px, py) -> spart
//  K4 k_xa     : flash-merge partials -> (m, 1/s) + pos; xa partials = attn^T @ x
//                with attn = exp(lg-m)*inv on the fly             (reads x, 201MB)
//                c-split grid (16 ns x 2 cs x 32 b): 30KB LDS -> 4 blocks/CU (R4: 2)
//  K5 k_values : xa = sum 16 slots of matching c-half; values; msgv   (512 blocks)
//  K6 k_agg    : per-dst aggregation over the 15 in-neighbors     (512 blocks)
//  K7 k_mlp    : silu MLP + layer_scale*o + values -> out         (512 blocks)
//
// R3 lesson: per-image tail fusion (32 blocks) = 1.5% occupancy, 227us. Tail stays 512-block.
// R4 lesson: k_xa at 2 blocks/CU is latency-serialized (VALUBusy 1%); LDS-staged qk in
// k_logits adds ds_read pressure for nothing (wave-uniform global reads -> s_load is free).
// Entire GNN branch is scaled by layer_scale=1e-6 before the residual, so __sinf/__expf
// precision there is irrelevant; the accuracy-critical path is values (f32).

#define Bsz 32
#define Cc  384
#define Nn  4096
#define Ee  256
#define NHh 16
#define HIDh 128

__device__ __forceinline__ float waveSum(float v){
#pragma unroll
  for(int o=32;o;o>>=1) v += __shfl_down(v,(unsigned)o,64);
  return v;
}
__device__ __forceinline__ float waveMaxAll(float v){
#pragma unroll
  for(int o=1;o<64;o<<=1) v = fmaxf(v, __shfl_xor(v,(unsigned)o,64));
  return v;
}
__device__ __forceinline__ float waveSumAll(float v){
#pragma unroll
  for(int o=1;o<64;o<<=1) v += __shfl_xor(v,(unsigned)o,64);
  return v;
}
__device__ __forceinline__ float blockSum(float v, float* sm){
  int lane = threadIdx.x & 63, w = threadIdx.x >> 6;
  int nw = blockDim.x >> 6;
  float r = waveSum(v);
  if(lane==0) sm[w] = r;
  __syncthreads();
  float s = 0.f;
  for(int i=0;i<nw;i++) s += sm[i];
  __syncthreads();
  return s;
}

// ---------------- K1: mean over pixels ----------------
__global__ __launch_bounds__(256) void k_mean(const float* __restrict__ x, float* __restrict__ xm){
  int bc = blockIdx.x, t = threadIdx.x;
  const float4* xr = (const float4*)(x + (size_t)bc*Nn);
  float s = 0.f;
#pragma unroll
  for(int i=0;i<4;i++){ float4 v = xr[t + 256*i]; s += (v.x+v.y) + (v.z+v.w); }
  __shared__ float sm[8];
  s = blockSum(s, sm);
  if(t==0) xm[bc] = s * (1.0f/4096.0f);
}

// ---------------- K2: q and folded qk (coalesced kw reads) ----------------
__global__ __launch_bounds__(384) void k_qk(const float* __restrict__ xm, const float* __restrict__ qw,
                                            const float* __restrict__ qb, const float* __restrict__ kw,
                                            float* __restrict__ qk_t){
  int b = blockIdx.x, t = threadIdx.x;
  __shared__ float xs[Cc];
  __shared__ float qs[Ee];
  if(t < 96) ((float4*)xs)[t] = ((const float4*)(xm + b*Cc))[t];
  __syncthreads();
  if(t < Ee){
    const float4* wr = (const float4*)(qw + (size_t)t*Cc);
    const float4* xv = (const float4*)xs;
    float a = qb[t];
#pragma unroll 4
    for(int c4=0;c4<96;c4++){ float4 w = wr[c4], xx = xv[c4]; a += w.x*xx.x + w.y*xx.y + w.z*xx.z + w.w*xx.w; }
    qs[t] = a;
  }
  __syncthreads();
  int c = t;
#pragma unroll
  for(int hq=0; hq<4; hq++){
    float r0, r1, r2, r3;
#pragma unroll
    for(int hh=0; hh<4; hh++){
      int h = hq*4 + hh;
      float a = 0.f;
#pragma unroll
      for(int d=0; d<16; d++) a += qs[h*16+d] * kw[(size_t)(h*16+d)*Cc + c];
      a *= 0.25f;
      if(hh==0) r0=a; else if(hh==1) r1=a; else if(hh==2) r2=a; else r3=a;
    }
    ((float4*)(qk_t + ((size_t)b*Cc + c)*16))[hq] = make_float4(r0,r1,r2,r3);
  }
}

// ---------------- K3: logits + per-block softmax partials ----------------
// grid (16, Bsz) = 512 blocks, 1 n/thread, unroll 8. qk reads are wave-uniform global
// float4 derefs -> compiler emits s_load (no LDS traffic, L1-resident).
// Epilogue: block reduces its 256 logits per h into (m, s, px, py) -> spart.
__global__ __launch_bounds__(256) void k_logits(const float* __restrict__ x, const float* __restrict__ qk_t,
                                                float* __restrict__ lg, float* __restrict__ spart){
  __shared__ float sl[16*256];      // 16 KB (stats transpose only)
  int b = blockIdx.y, ns = blockIdx.x, t = threadIdx.x;
  int n = ns*256 + t;
  float acc[16];
#pragma unroll
  for(int h=0;h<16;h++) acc[h] = 0.f;
  const float* xb = x + (size_t)b*Cc*Nn + n;
  const float4* qk = (const float4*)(qk_t + (size_t)b*Cc*16);
#pragma unroll 8
  for(int c=0;c<Cc;c++){
    float xv = xb[(size_t)c*Nn];               // coalesced, streamed once
    float4 q0 = qk[c*4+0], q1 = qk[c*4+1], q2 = qk[c*4+2], q3 = qk[c*4+3]; // wave-uniform -> s_load
    acc[0]  += xv*q0.x; acc[1]  += xv*q0.y; acc[2]  += xv*q0.z; acc[3]  += xv*q0.w;
    acc[4]  += xv*q1.x; acc[5]  += xv*q1.y; acc[6]  += xv*q1.z; acc[7]  += xv*q1.w;
    acc[8]  += xv*q2.x; acc[9]  += xv*q2.y; acc[10] += xv*q2.z; acc[11] += xv*q2.w;
    acc[12] += xv*q3.x; acc[13] += xv*q3.y; acc[14] += xv*q3.z; acc[15] += xv*q3.w;
  }
#pragma unroll
  for(int h=0;h<16;h++) lg[((size_t)(b*16+h))*Nn + n] = acc[h];

  // ---- stats partials: transpose through LDS, wave w reduces h = w*4..w*4+3 ----
#pragma unroll
  for(int h=0;h<16;h++) sl[h*256 + t] = acc[h];
  __syncthreads();
  int w = t >> 6, lane = t & 63;
#pragma unroll
  for(int hh=0; hh<4; hh++){
    int h = w*4 + hh;
    float v0 = sl[h*256 + lane], v1 = sl[h*256 + 64 + lane];
    float v2 = sl[h*256 + 128 + lane], v3 = sl[h*256 + 192 + lane];
    float m = waveMaxAll(fmaxf(fmaxf(v0,v1), fmaxf(v2,v3)));
    float e0 = __expf(v0-m), e1 = __expf(v1-m), e2 = __expf(v2-m), e3 = __expf(v3-m);
    // n = ns*256 + quarter*64 + lane -> row = n>>6 = ns*4+quarter, col = n&63 = lane
    float row0 = (float)(ns*4);
    float col  = (float)lane;
    float s  = (e0+e1)+(e2+e3);
    float px = e0*row0 + e1*(row0+1.f) + e2*(row0+2.f) + e3*(row0+3.f);
    float py = s * col;
    float s_t  = waveSumAll(s);
    float px_t = waveSumAll(px);
    float py_t = waveSumAll(py);
    if(lane==0)
      *(float4*)(spart + ((size_t)(b*16+h)*16 + ns)*4) = make_float4(m, s_t, px_t, py_t);
  }
}

// ---------------- K4: xa partials = attn^T @ x, attn computed on the fly ----------------
// grid (32, Bsz): bx = ns (0..15) | cs<<4. Block owns 192 c x 256 n. LDS 30KB -> 4 blocks/CU.
// Prologue: flash-merge the 16 per-block partials -> (m, 1/s); bx==0 writes pos.
#define XROW 36
#define CSPL 192
#define SLOTSZ (512*CSPL)
__global__ __launch_bounds__(256) void k_xa(const float* __restrict__ x, const float* __restrict__ lg,
                                            const float* __restrict__ spart, float* __restrict__ pos,
                                            float* __restrict__ part){
  __shared__ float xl[CSPL*XROW]; // 27.6 KB
  __shared__ float al[NHh*XROW];  // 2.3 KB
  __shared__ float ss[32];
  int b = blockIdx.y, t = threadIdx.x;
  int ns = blockIdx.x & 15, cs = blockIdx.x >> 4;
  int th = t & 3, tc = t >> 2;
  if(t < 64){                      // wave 0: 4 lanes per h merge 16 partials
    int h = t >> 2, qq = t & 3;
    const float4* sp = (const float4*)spart + (size_t)(b*16+h)*16 + qq*4;
    float4 p0 = sp[0], p1 = sp[1], p2 = sp[2], p3 = sp[3];
    float m = fmaxf(fmaxf(p0.x,p1.x), fmaxf(p2.x,p3.x));
    m = fmaxf(m, __shfl_xor(m, 1u, 64));
    m = fmaxf(m, __shfl_xor(m, 2u, 64));
    float w0 = __expf(p0.x-m), w1 = __expf(p1.x-m), w2 = __expf(p2.x-m), w3 = __expf(p3.x-m);
    float s  = p0.y*w0 + p1.y*w1 + p2.y*w2 + p3.y*w3;
    float px = p0.z*w0 + p1.z*w1 + p2.z*w2 + p3.z*w3;
    float py = p0.w*w0 + p1.w*w1 + p2.w*w2 + p3.w*w3;
    s  += __shfl_xor(s, 1u, 64);  s  += __shfl_xor(s, 2u, 64);
    px += __shfl_xor(px,1u, 64);  px += __shfl_xor(px,2u, 64);
    py += __shfl_xor(py,1u, 64);  py += __shfl_xor(py,2u, 64);
    if(qq==0){
      float inv = 1.0f/s;
      ss[h*2] = m; ss[h*2+1] = inv;
      if(blockIdx.x==0){ pos[(b*16+h)*2] = px*inv; pos[(b*16+h)*2+1] = py*inv; }
    }
  }
  __syncthreads();
  int ah = t >> 3, aj = t & 7;
  float mA = 0.f, iA = 0.f;
  if(t < 128){ mA = ss[ah*2]; iA = ss[ah*2+1]; }
  float acc[4][3];
#pragma unroll
  for(int k=0;k<4;k++)
#pragma unroll
    for(int m=0;m<3;m++) acc[k][m] = 0.f;

  float4 xr[6];
  float4 ar = make_float4(0,0,0,0);
  const float* xbase = x + ((size_t)b*Cc + (size_t)cs*CSPL)*Nn;

  auto LOAD = [&](int ch){
    int n0 = ns*256 + ch*32;
    if(t < 128)
      ar = *(const float4*)(lg + ((size_t)(b*16+ah))*Nn + n0 + aj*4);
#pragma unroll
    for(int i=0;i<6;i++){
      int f = t + 256*i;
      int c = f >> 3, j4 = f & 7;
      xr[i] = *(const float4*)(xbase + (size_t)c*Nn + n0 + j4*4);
    }
  };

  LOAD(0);
  for(int ch=0; ch<8; ch++){
    if(t < 128){
      float4 e;
      e.x = __expf(ar.x - mA)*iA;
      e.y = __expf(ar.y - mA)*iA;
      e.z = __expf(ar.z - mA)*iA;
      e.w = __expf(ar.w - mA)*iA;
      *(float4*)(al + ah*XROW + aj*4) = e;
    }
#pragma unroll
    for(int i=0;i<6;i++){
      int f = t + 256*i;
      int c = f >> 3, j4 = f & 7;
      *(float4*)(xl + c*XROW + j4*4) = xr[i];
    }
    __syncthreads();
    if(ch < 7) LOAD(ch+1);           // next chunk's loads in flight under compute
#pragma unroll
    for(int j4=0;j4<8;j4++){
      float4 a4[4], x4[3];
#pragma unroll
      for(int k=0;k<4;k++) a4[k] = *(const float4*)(al + (th+4*k)*XROW + j4*4);
#pragma unroll
      for(int m=0;m<3;m++) x4[m] = *(const float4*)(xl + (tc+64*m)*XROW + j4*4);
#pragma unroll
      for(int k=0;k<4;k++)
#pragma unroll
        for(int m=0;m<3;m++)
          acc[k][m] += a4[k].x*x4[m].x + a4[k].y*x4[m].y + a4[k].z*x4[m].z + a4[k].w*x4[m].w;
    }
    __syncthreads();
  }
  size_t slot = (size_t)(cs*16 + ns)*SLOTSZ;
#pragma unroll
  for(int k=0;k<4;k++)
#pragma unroll
    for(int m=0;m<3;m++)
      part[slot + (size_t)(b*16 + th + 4*k)*CSPL + (tc + 64*m)] = acc[k][m];
}

// ---------------- K5: xa reduce (16 slots of matching c-half) + values + msgv ----------------
__global__ __launch_bounds__(256) void k_values(const float* __restrict__ part, const float* __restrict__ vw,
                                                const float* __restrict__ vb, const float* __restrict__ msg_w,
                                                const float* __restrict__ msg_b,
                                                float* __restrict__ values, float* __restrict__ msgv){
  int node = blockIdx.x, t = threadIdx.x;
  __shared__ float xa[Cc];
  __shared__ float vs[Ee];
  if(t < 96){
    int half = (t >= 48);
    const float* base = part + (size_t)(half*16)*SLOTSZ + (size_t)node*CSPL + (t*4 - half*CSPL);
    float4 s = make_float4(0,0,0,0);
#pragma unroll
    for(int p=0;p<16;p++){
      float4 v = *(const float4*)(base + (size_t)p*SLOTSZ);
      s.x += v.x; s.y += v.y; s.z += v.z; s.w += v.w;
    }
    *(float4*)(xa + t*4) = s;
  }
  __syncthreads();
  {
    const float4* wr = (const float4*)(vw + (size_t)t*Cc);
    const float4* xv = (const float4*)xa;
    float a = vb[t];
#pragma unroll 4
    for(int c4=0;c4<96;c4++){ float4 w = wr[c4], xx = xv[c4]; a += w.x*xx.x + w.y*xx.y + w.z*xx.z + w.w*xx.w; }
    values[(size_t)node*Ee + t] = a;
    vs[t] = a;
  }
  __syncthreads();
  if(t < HIDh){
    const float4* mr = (const float4*)(msg_w + (size_t)t*Ee);
    const float4* vv = (const float4*)vs;
    float a = msg_b[t];
#pragma unroll 4
    for(int e4=0;e4<64;e4++){ float4 w = mr[e4], xx = vv[e4]; a += w.x*xx.x + w.y*xx.y + w.z*xx.z + w.w*xx.w; }
    msgv[(size_t)node*HIDh + t] = a;
  }
}

// ---------------- K6: graph aggregation (mean over 15 in-neighbors) ----------------
__global__ __launch_bounds__(128) void k_agg(const float* __restrict__ pos, const float* __restrict__ msgv,
                                             const float* __restrict__ brff, const float* __restrict__ emb_w,
                                             float* __restrict__ agg){
  int node = blockIdx.x, t = threadIdx.x;
  int b = node >> 4, jj = node & 15;
  __shared__ float ps[32];
  __shared__ float bf[64];
  __shared__ float mv[16*HIDh];
  __shared__ float ea[64];
  if(t < 32) ps[t] = pos[b*32 + t];
  if(t < 64) bf[t] = brff[t];
#pragma unroll
  for(int i=0;i<4;i++){ int f = t + 128*i; ((float4*)mv)[f] = ((const float4*)(msgv + (size_t)b*16*HIDh))[f]; }
  float4 er[16];
#pragma unroll
  for(int i=0;i<16;i++) er[i] = ((const float4*)(emb_w + (size_t)t*64))[i];
  __syncthreads();
  float pxj = ps[jj*2], pyj = ps[jj*2+1];
  float acc = 0.f;
  for(int i=0;i<16;i++){
    if(i == jj) continue;            // jj is block-uniform: barriers stay aligned
    float rx = ps[i*2]   - pxj;
    float ry = ps[i*2+1] - pyj;
    __syncthreads();
    if(t < 32){
      float pr = rx*bf[t*2] + ry*bf[t*2+1];
      ea[t]    = 1.41421356f * __sinf(pr);
      ea[t+32] = 1.41421356f * __cosf(pr);
    }
    __syncthreads();
    float psi = 0.f;
    const float4* eav = (const float4*)ea;
#pragma unroll
    for(int k=0;k<16;k++){ float4 e4 = eav[k]; psi += e4.x*er[k].x + e4.y*er[k].y + e4.z*er[k].z + e4.w*er[k].w; }
    acc += mv[i*HIDh + t] * psi;
  }
  agg[(size_t)node*HIDh + t] = acc * (1.0f/15.0f);
}

// ---------------- K7: MLP + layer scale + residual ----------------
__global__ __launch_bounds__(256) void k_mlp(const float* __restrict__ agg, const float* __restrict__ l1w,
                                             const float* __restrict__ l1b, const float* __restrict__ l2w,
                                             const float* __restrict__ l2b, const float* __restrict__ ls,
                                             const float* __restrict__ values, float* __restrict__ out){
  int node = blockIdx.x, t = threadIdx.x;
  __shared__ float ag[HIDh];
  __shared__ float h1[512];
  if(t < 32) ((float4*)ag)[t] = ((const float4*)(agg + (size_t)node*HIDh))[t];
  __syncthreads();
#pragma unroll
  for(int r=0;r<2;r++){
    int u = t + r*256;
    const float4* wr = (const float4*)(l1w + (size_t)u*HIDh);
    const float4* av = (const float4*)ag;
    float a = l1b[u];
#pragma unroll 4
    for(int k=0;k<32;k++){ float4 w = wr[k], xx = av[k]; a += w.x*xx.x + w.y*xx.y + w.z*xx.z + w.w*xx.w; }
    h1[u] = a / (1.0f + __expf(-a));   // silu
  }
  __syncthreads();
  {
    const float4* wr = (const float4*)(l2w + (size_t)t*512);
    const float4* hv = (const float4*)h1;
    float o = l2b[t];
#pragma unroll 4
    for(int k=0;k<128;k++){ float4 w = wr[k], xx = hv[k]; o += w.x*xx.x + w.y*xx.y + w.z*xx.z + w.w*xx.w; }
    size_t oi = (size_t)node*Ee + t;
    out[oi] = ls[t]*o + values[oi];
  }
}

extern "C" void kernel_launch(void* const* d_in, const int* in_sizes, int n_in,
                              void* d_out, int out_size, void* d_ws, size_t ws_size,
                              hipStream_t stream) {
  const float* x    = (const float*)d_in[0];
  const float* qw   = (const float*)d_in[1];
  const float* qb   = (const float*)d_in[2];
  const float* kw   = (const float*)d_in[3];
  // d_in[4] = kb: adds a per-(b,h) constant to logits -> cancels in softmax; unused.
  const float* vw   = (const float*)d_in[5];
  const float* vb   = (const float*)d_in[6];
  const float* brff = (const float*)d_in[7];
  const float* msgw = (const float*)d_in[8];
  const float* msgb = (const float*)d_in[9];
  const float* embw = (const float*)d_in[10];
  const float* l1w  = (const float*)d_in[11];
  const float* l1b  = (const float*)d_in[12];
  const float* l2w  = (const float*)d_in[13];
  const float* l2b  = (const float*)d_in[14];
  const float* lsc  = (const float*)d_in[15];
  // d_in[16], d_in[17] = edge_src/edge_dst: deterministic fully-connected graph; handled structurally.

  float* W      = (float*)d_ws;
  float* xm     = W;                    // 12288
  float* qkt    = xm  + 12288;          // 196608
  float* lg     = qkt + 196608;         // 2097152 (raw logits; never normalized in memory)
  float* pos    = lg  + 2097152;        // 1024
  float* spart  = pos + 1024;           // 512 nodes * 16 blocks * 4 = 32768
  float* part   = spart + 32768;        // 32 slots * 512 nodes * 192 c = 3145728
  float* values = part + 3145728;       // 131072
  float* msgv   = values + 131072;      // 65536
  float* agg    = msgv + 65536;         // 65536  (total ~22 MiB)
  float* out    = (float*)d_out;

  k_mean  <<<Bsz*Cc, 256, 0, stream>>>(x, xm);
  k_qk    <<<Bsz, 384, 0, stream>>>(xm, qw, qb, kw, qkt);
  k_logits<<<dim3(16, Bsz), 256, 0, stream>>>(x, qkt, lg, spart);
  k_xa    <<<dim3(32, Bsz), 256, 0, stream>>>(x, lg, spart, pos, part);
  k_values<<<Bsz*NHh, 256, 0, stream>>>(part, vw, vb, msgw, msgb, values, msgv);
  k_agg   <<<Bsz*NHh, 128, 0, stream>>>(pos, msgv, brff, embw, agg);
  k_mlp   <<<Bsz*NHh, 256, 0, stream>>>(agg, l1w, l1b, l2w, l2b, lsc, values, out);
}